// Round 1
// baseline (1788.016 us; speedup 1.0000x reference)
//
#include <hip/hip_runtime.h>
#include <math.h>

#define TT  64
#define CC  128
#define HH  8
#define HDD 16
#define FFD 512

__device__ __forceinline__ float dot4(float4 a, float4 b) {
    return a.x*b.x + a.y*b.y + a.z*b.z + a.w*b.w;
}
__device__ __forceinline__ float gelu_exact(float v) {
    return 0.5f * v * (1.0f + erff(v * 0.70710678118654752f));
}

// One block per batch element. 512 threads = 8 waves.
// LDS: hb (LN out / h2), ab (attn concat, then x2), r3 (qkv+scores, then f1 chunk).
__global__ __launch_bounds__(512, 1) void block_fused(
    const float* __restrict__ x,
    const float* __restrict__ wq, const float* __restrict__ wk, const float* __restrict__ wv,
    const float* __restrict__ wp, const float* __restrict__ bp,
    const float* __restrict__ w1, const float* __restrict__ b1,
    const float* __restrict__ w2, const float* __restrict__ b2,
    const float* __restrict__ g1, const float* __restrict__ be1,
    const float* __restrict__ g2, const float* __restrict__ be2,
    float* __restrict__ out)
{
    __shared__ float hb[TT*CC];     // 32 KB
    __shared__ float ab[TT*CC];     // 32 KB
    __shared__ float r3[8448];      // 33 KB: {q,k,v,scores} or f1 chunk [64][132]

    const int tid  = threadIdx.x;
    const int lane = tid & 63;
    const int wave = tid >> 6;

    const float* xb = x   + (size_t)blockIdx.x * (TT*CC);
    float*       ob = out + (size_t)blockIdx.x * (TT*CC);

    // ---------------- LN1: wave w owns rows w*8 .. w*8+7 ----------------
    for (int r = wave*8; r < wave*8 + 8; ++r) {
        float v0 = xb[r*CC + lane];
        float v1 = xb[r*CC + lane + 64];
        float s = v0 + v1;
        #pragma unroll
        for (int off = 32; off; off >>= 1) s += __shfl_xor(s, off);
        float mean = s * (1.0f/CC);
        float d0 = v0 - mean, d1 = v1 - mean;
        float sq = d0*d0 + d1*d1;
        #pragma unroll
        for (int off = 32; off; off >>= 1) sq += __shfl_xor(sq, off);
        float rstd = rsqrtf(sq * (1.0f/CC) + 1e-5f);
        hb[r*CC + lane]      = g1[lane]    * (d0*rstd) + be1[lane];
        hb[r*CC + lane + 64] = g1[lane+64] * (d1*rstd) + be1[lane+64];
    }
    __syncthreads();

    float* qs = r3;                 // [64][16]
    float* ks = r3 + TT*HDD;        // [64][16]
    float* vs = r3 + 2*TT*HDD;      // [64][16]
    float* sc = r3 + 3*TT*HDD;      // [64][65] padded (softmax probs)

    // ---------------- attention, head by head ----------------
    for (int h = 0; h < HH; ++h) {
        const float* wqh = wq + h*CC*HDD;
        const float* wkh = wk + h*CC*HDD;
        const float* wvh = wv + h*CC*HDD;

        // q,k,v projections: thread -> col = tid&15, rows tid>>4 and +32
        {
            const int col = tid & 15;
            const int r0  = tid >> 4;
            #pragma unroll
            for (int rr = 0; rr < 2; ++rr) {
                const int r = r0 + rr*32;
                float aq = 0.f, ak = 0.f, av = 0.f;
                for (int c = 0; c < CC; c += 4) {
                    float4 hv = *(const float4*)&hb[r*CC + c];
                    aq += hv.x * wqh[(c+0)*HDD + col];
                    ak += hv.x * wkh[(c+0)*HDD + col];
                    av += hv.x * wvh[(c+0)*HDD + col];
                    aq += hv.y * wqh[(c+1)*HDD + col];
                    ak += hv.y * wkh[(c+1)*HDD + col];
                    av += hv.y * wvh[(c+1)*HDD + col];
                    aq += hv.z * wqh[(c+2)*HDD + col];
                    ak += hv.z * wkh[(c+2)*HDD + col];
                    av += hv.z * wvh[(c+2)*HDD + col];
                    aq += hv.w * wqh[(c+3)*HDD + col];
                    ak += hv.w * wkh[(c+3)*HDD + col];
                    av += hv.w * wvh[(c+3)*HDD + col];
                }
                qs[r*HDD + col] = aq;
                ks[r*HDD + col] = ak;
                vs[r*HDD + col] = av;
            }
        }
        __syncthreads();

        // scores + causal softmax: wave w owns rows w*8..w*8+7; lane = key index
        {
            float4 kr0 = *(const float4*)&ks[lane*HDD + 0];
            float4 kr1 = *(const float4*)&ks[lane*HDD + 4];
            float4 kr2 = *(const float4*)&ks[lane*HDD + 8];
            float4 kr3 = *(const float4*)&ks[lane*HDD + 12];
            for (int r = wave*8; r < wave*8 + 8; ++r) {
                float4 q0 = *(const float4*)&qs[r*HDD + 0];
                float4 q1 = *(const float4*)&qs[r*HDD + 4];
                float4 q2 = *(const float4*)&qs[r*HDD + 8];
                float4 q3 = *(const float4*)&qs[r*HDD + 12];
                float acc = dot4(q0,kr0) + dot4(q1,kr1) + dot4(q2,kr2) + dot4(q3,kr3);
                float sv = (lane <= r) ? acc * 0.25f : -INFINITY;
                float m = sv;
                #pragma unroll
                for (int off = 32; off; off >>= 1) m = fmaxf(m, __shfl_xor(m, off));
                float e = (lane <= r) ? __expf(sv - m) : 0.f;
                float ssum = e;
                #pragma unroll
                for (int off = 32; off; off >>= 1) ssum += __shfl_xor(ssum, off);
                sc[r*65 + lane] = e / ssum;
            }
        }
        __syncthreads();

        // attn = P @ V -> ab[:, h*16 : h*16+16]
        {
            const int col = tid & 15;
            const int r0  = tid >> 4;
            #pragma unroll
            for (int rr = 0; rr < 2; ++rr) {
                const int r = r0 + rr*32;
                float acc = 0.f;
                for (int s = 0; s <= r; ++s)
                    acc += sc[r*65 + s] * vs[s*HDD + col];
                ab[r*CC + h*HDD + col] = acc;
            }
        }
        __syncthreads();
    }

    // ---------------- proj + residual: x2 = x + ab @ wp + bp ----------------
    const int rt = tid >> 5;   // 0..15 -> rows rt*4 .. rt*4+3
    const int ct = tid & 31;   // cols ct*4 .. ct*4+3
    float4 x2v[4];
    {
        float acc[4][4] = {};
        for (int k = 0; k < CC; k += 4) {
            float4 av[4], wl[4];
            #pragma unroll
            for (int rr = 0; rr < 4; ++rr) av[rr] = *(const float4*)&ab[(rt*4+rr)*CC + k];
            #pragma unroll
            for (int kk = 0; kk < 4; ++kk) wl[kk] = *(const float4*)&wp[(k+kk)*CC + ct*4];
            #pragma unroll
            for (int rr = 0; rr < 4; ++rr) {
                const float* ap = (const float*)&av[rr];
                #pragma unroll
                for (int kk = 0; kk < 4; ++kk) {
                    float a = ap[kk];
                    acc[rr][0] += a * wl[kk].x;
                    acc[rr][1] += a * wl[kk].y;
                    acc[rr][2] += a * wl[kk].z;
                    acc[rr][3] += a * wl[kk].w;
                }
            }
        }
        float4 bpv = *(const float4*)&bp[ct*4];
        #pragma unroll
        for (int rr = 0; rr < 4; ++rr) {
            float4 xv = *(const float4*)&xb[(rt*4+rr)*CC + ct*4];
            x2v[rr].x = xv.x + acc[rr][0] + bpv.x;
            x2v[rr].y = xv.y + acc[rr][1] + bpv.y;
            x2v[rr].z = xv.z + acc[rr][2] + bpv.z;
            x2v[rr].w = xv.w + acc[rr][3] + bpv.w;
        }
    }
    __syncthreads();           // everyone done reading ab (attn)
    #pragma unroll
    for (int rr = 0; rr < 4; ++rr)
        *(float4*)&ab[(rt*4+rr)*CC + ct*4] = x2v[rr];   // ab now holds x2
    __syncthreads();

    // ---------------- LN2: ab(x2) -> hb(h2) ----------------
    for (int r = wave*8; r < wave*8 + 8; ++r) {
        float v0 = ab[r*CC + lane];
        float v1 = ab[r*CC + lane + 64];
        float s = v0 + v1;
        #pragma unroll
        for (int off = 32; off; off >>= 1) s += __shfl_xor(s, off);
        float mean = s * (1.0f/CC);
        float d0 = v0 - mean, d1 = v1 - mean;
        float sq = d0*d0 + d1*d1;
        #pragma unroll
        for (int off = 32; off; off >>= 1) sq += __shfl_xor(sq, off);
        float rstd = rsqrtf(sq * (1.0f/CC) + 1e-5f);
        hb[r*CC + lane]      = g2[lane]    * (d0*rstd) + be2[lane];
        hb[r*CC + lane + 64] = g2[lane+64] * (d1*rstd) + be2[lane+64];
    }
    __syncthreads();

    // ---------------- FF: out = x2 + gelu(h2@w1+b1)@w2 + b2 ----------------
    float* f1 = r3;            // [64][132] padded, per 128-col chunk
    float facc[4][4] = {};
    for (int jc = 0; jc < 4; ++jc) {
        // compute gelu(h2 @ w1 chunk + b1) into registers first
        float c1[4][4] = {};
        for (int k = 0; k < CC; k += 4) {
            float4 av[4], wl[4];
            #pragma unroll
            for (int rr = 0; rr < 4; ++rr) av[rr] = *(const float4*)&hb[(rt*4+rr)*CC + k];
            #pragma unroll
            for (int kk = 0; kk < 4; ++kk) wl[kk] = *(const float4*)&w1[(k+kk)*FFD + jc*128 + ct*4];
            #pragma unroll
            for (int rr = 0; rr < 4; ++rr) {
                const float* ap = (const float*)&av[rr];
                #pragma unroll
                for (int kk = 0; kk < 4; ++kk) {
                    float a = ap[kk];
                    c1[rr][0] += a * wl[kk].x;
                    c1[rr][1] += a * wl[kk].y;
                    c1[rr][2] += a * wl[kk].z;
                    c1[rr][3] += a * wl[kk].w;
                }
            }
        }
        float4 b1v = *(const float4*)&b1[jc*128 + ct*4];
        __syncthreads();       // previous chunk's ff2 reads (or attn-phase r3 use) done
        #pragma unroll
        for (int rr = 0; rr < 4; ++rr) {
            float4 o;
            o.x = gelu_exact(c1[rr][0] + b1v.x);
            o.y = gelu_exact(c1[rr][1] + b1v.y);
            o.z = gelu_exact(c1[rr][2] + b1v.z);
            o.w = gelu_exact(c1[rr][3] + b1v.w);
            *(float4*)&f1[(rt*4+rr)*132 + ct*4] = o;
        }
        __syncthreads();

        // facc += f1 @ w2 chunk
        for (int j = 0; j < 128; j += 4) {
            float4 fv[4], wl[4];
            #pragma unroll
            for (int rr = 0; rr < 4; ++rr) fv[rr] = *(const float4*)&f1[(rt*4+rr)*132 + j];
            #pragma unroll
            for (int jj = 0; jj < 4; ++jj) wl[jj] = *(const float4*)&w2[(jc*128 + j + jj)*CC + ct*4];
            #pragma unroll
            for (int rr = 0; rr < 4; ++rr) {
                const float* fp = (const float*)&fv[rr];
                #pragma unroll
                for (int jj = 0; jj < 4; ++jj) {
                    float a = fp[jj];
                    facc[rr][0] += a * wl[jj].x;
                    facc[rr][1] += a * wl[jj].y;
                    facc[rr][2] += a * wl[jj].z;
                    facc[rr][3] += a * wl[jj].w;
                }
            }
        }
    }

    float4 b2v = *(const float4*)&b2[ct*4];
    #pragma unroll
    for (int rr = 0; rr < 4; ++rr) {
        float4 xv2 = *(const float4*)&ab[(rt*4+rr)*CC + ct*4];   // x2
        float4 o;
        o.x = xv2.x + facc[rr][0] + b2v.x;
        o.y = xv2.y + facc[rr][1] + b2v.y;
        o.z = xv2.z + facc[rr][2] + b2v.z;
        o.w = xv2.w + facc[rr][3] + b2v.w;
        *(float4*)&ob[(rt*4+rr)*CC + ct*4] = o;
    }
}

extern "C" void kernel_launch(void* const* d_in, const int* in_sizes, int n_in,
                              void* d_out, int out_size, void* d_ws, size_t ws_size,
                              hipStream_t stream) {
    (void)n_in; (void)out_size; (void)d_ws; (void)ws_size;
    const float* x   = (const float*)d_in[0];
    const float* wq  = (const float*)d_in[1];
    const float* wk  = (const float*)d_in[2];
    const float* wv  = (const float*)d_in[3];
    const float* wp  = (const float*)d_in[4];
    const float* bp  = (const float*)d_in[5];
    const float* w1  = (const float*)d_in[6];
    const float* b1  = (const float*)d_in[7];
    const float* w2  = (const float*)d_in[8];
    const float* b2  = (const float*)d_in[9];
    const float* g1  = (const float*)d_in[10];
    const float* be1 = (const float*)d_in[11];
    const float* g2  = (const float*)d_in[12];
    const float* be2 = (const float*)d_in[13];

    const int B = in_sizes[0] / (TT*CC);
    block_fused<<<dim3(B), dim3(512), 0, stream>>>(
        x, wq, wk, wv, wp, bp, w1, b1, w2, b2, g1, be1, g2, be2, (float*)d_out);
}

// Round 2
// 349.728 us; speedup vs baseline: 5.1126x; 5.1126x over previous
//
#include <hip/hip_runtime.h>
#include <math.h>

#define TT  64
#define CC  128
#define HH  8
#define RLD 136            // halves stride for [128][*] bf16 LDS tiles (272B = 17*16B)
#define VLD 72             // halves stride for vT / P buffers (144B = 9*16B)

typedef __attribute__((ext_vector_type(8))) short bf16x8;
typedef __attribute__((ext_vector_type(4))) float f32x4;

#define MFMA16(a, b, c) __builtin_amdgcn_mfma_f32_16x16x32_bf16((a), (b), (c), 0, 0, 0)

__device__ __forceinline__ unsigned short f2bf(float f) {
    unsigned int u = __float_as_uint(f);
    u += 0x7FFFu + ((u >> 16) & 1u);       // round-to-nearest-even
    return (unsigned short)(u >> 16);
}
__device__ __forceinline__ float bf2f(unsigned short h) {
    return __uint_as_float(((unsigned int)h) << 16);
}
__device__ __forceinline__ float gelu_exact(float v) {
    return 0.5f * v * (1.0f + erff(v * 0.70710678118654752f));
}

// ---- weight pre-pack: fragment-major bf16 ----
// dst[((nt*KT + kt)*64 + lane)*8 + j] = W[kt*32 + (lane>>4)*8 + j][nt*16 + (lane&15)]
// mode 0: W row-major [K][N]; mode 1: qkv [H][K][16] with n = h*16 + d
__global__ void pack_w(const float* __restrict__ src, unsigned short* __restrict__ dst,
                       int K, int N, int mode) {
    int i = blockIdx.x * 256 + threadIdx.x;
    if (i >= K * N) return;
    int j   = i & 7;
    int l   = (i >> 3) & 63;
    int tkt = i >> 9;
    int KT  = K >> 5;
    int nt  = tkt / KT;
    int kt  = tkt - nt * KT;
    int k   = kt * 32 + (l >> 4) * 8 + j;
    int n   = nt * 16 + (l & 15);
    float v = (mode == 0) ? src[k * N + n]
                          : src[(n >> 4) * (K * 16) + k * 16 + (n & 15)];
    dst[i] = f2bf(v);
}

// packed-weight half offsets in d_ws
#define OQ  0
#define OKk 16384
#define OV  32768
#define OP  49152
#define O1  65536
#define O2  131072

// One block = 2 batch elements (128 rows). 512 threads = 8 waves.
__global__ __launch_bounds__(512, 1) void block_fused(
    const float* __restrict__ x,
    const unsigned short* __restrict__ wpk,
    const float* __restrict__ bp,
    const float* __restrict__ b1, const float* __restrict__ b2,
    const float* __restrict__ g1, const float* __restrict__ be1,
    const float* __restrict__ g2, const float* __restrict__ be2,
    float* __restrict__ out)
{
    __shared__ __align__(16) unsigned short hB[128 * RLD];   // LN1 out -> attn concat -> proj A
    __shared__ __align__(16) unsigned short qB[128 * RLD];   // q -> h2 (LN2 out)
    __shared__ __align__(16) unsigned short kB[128 * RLD];   // k -> x2
    __shared__ __align__(16) unsigned short vB[256 * VLD];   // vT [(pair*16+d)][s] -> f1 chunk
    __shared__ __align__(16) unsigned short pB[8 * 16 * VLD];// per-wave P tile [16][64]

    const int tid  = threadIdx.x;
    const int lane = tid & 63;
    const int wave = tid >> 6;
    const int l15  = lane & 15;
    const int lg   = lane >> 4;

    const float* xb = x   + (size_t)blockIdx.x * (128 * CC);
    float*       ob = out + (size_t)blockIdx.x * (128 * CC);

    // ---------------- LN1: x -> hB (bf16) ----------------
    {
        float ga = g1[lane], gb = g1[lane + 64], ba = be1[lane], bb = be1[lane + 64];
        for (int r = wave * 16; r < wave * 16 + 16; ++r) {
            float v0 = xb[r * CC + lane], v1 = xb[r * CC + lane + 64];
            float s = v0 + v1;
            #pragma unroll
            for (int off = 32; off; off >>= 1) s += __shfl_xor(s, off);
            float mean = s * (1.0f / CC);
            float d0 = v0 - mean, d1 = v1 - mean;
            float sq = d0 * d0 + d1 * d1;
            #pragma unroll
            for (int off = 32; off; off >>= 1) sq += __shfl_xor(sq, off);
            float rstd = rsqrtf(sq * (1.0f / CC) + 1e-5f);
            hB[r * RLD + lane]      = f2bf(ga * (d0 * rstd) + ba);
            hB[r * RLD + lane + 64] = f2bf(gb * (d1 * rstd) + bb);
        }
    }
    __syncthreads();

    const int rt0 = (wave >> 1) * 2;   // wave's row-tile pair: rows rt0*16 .. rt0*16+31
    const int cg  = wave & 1;          // column-group split

    // ---------------- QKV: hB @ Wqkv -> qB, kB, vB(T) ----------------
    {
        bf16x8 la[2][4];
        #pragma unroll
        for (int i = 0; i < 2; ++i)
            #pragma unroll
            for (int kt = 0; kt < 4; ++kt)
                la[i][kt] = *(const bf16x8*)&hB[((rt0 + i) * 16 + l15) * RLD + kt * 32 + lg * 8];

        #pragma unroll 1
        for (int ntl = 0; ntl < 12; ++ntl) {
            int nt = cg * 12 + ntl;                 // 0..23: 0-7 q, 8-15 k, 16-23 v
            int sec = nt >> 3, ntn = nt & 7;
            const unsigned short* wb = wpk + sec * 16384;
            f32x4 c0 = {0.f,0.f,0.f,0.f}, c1 = {0.f,0.f,0.f,0.f};
            #pragma unroll
            for (int kt = 0; kt < 4; ++kt) {
                bf16x8 b = *(const bf16x8*)&wb[((ntn * 4 + kt) * 64 + lane) * 8];
                c0 = MFMA16(la[0][kt], b, c0);
                c1 = MFMA16(la[1][kt], b, c1);
            }
            int row0 = rt0 * 16 + lg * 4;
            if (sec == 0) {
                #pragma unroll
                for (int r = 0; r < 4; ++r) {
                    qB[(row0 + r)      * RLD + ntn * 16 + l15] = f2bf(c0[r]);
                    qB[(row0 + 16 + r) * RLD + ntn * 16 + l15] = f2bf(c1[r]);
                }
            } else if (sec == 1) {
                #pragma unroll
                for (int r = 0; r < 4; ++r) {
                    kB[(row0 + r)      * RLD + ntn * 16 + l15] = f2bf(c0[r]);
                    kB[(row0 + 16 + r) * RLD + ntn * 16 + l15] = f2bf(c1[r]);
                }
            } else {   // v, stored transposed: vB[(pair*16 + d)*VLD + s]
                #pragma unroll
                for (int r = 0; r < 4; ++r) {
                    int ra = row0 + r, rb = row0 + 16 + r;
                    vB[(((ra >> 6) * 8 + ntn) * 16 + l15) * VLD + (ra & 63)] = f2bf(c0[r]);
                    vB[(((rb >> 6) * 8 + ntn) * 16 + l15) * VLD + (rb & 63)] = f2bf(c1[r]);
                }
            }
        }
    }
    __syncthreads();

    // ---------------- attention: per wave, pairs {wave, wave+8} ----------------
    {
        unsigned short* pw = pB + wave * 16 * VLD;
        #pragma unroll 1
        for (int pi = 0; pi < 2; ++pi) {
            int p = wave + pi * 8;
            int bb = p >> 3, h = p & 7;
            int rbase = bb * 64;
            #pragma unroll 1
            for (int mt = 0; mt < 4; ++mt) {
                // scores: S = q @ k^T (K=16, lanes>=32 contribute zeros)
                f32x4 sfr[4];
                #pragma unroll
                for (int st = 0; st < 4; ++st) sfr[st] = (f32x4){0.f,0.f,0.f,0.f};
                bf16x8 zf = {0,0,0,0,0,0,0,0};
                bf16x8 aq = zf;
                if (lane < 32)
                    aq = *(const bf16x8*)&qB[(rbase + mt * 16 + l15) * RLD + h * 16 + lg * 8];
                #pragma unroll
                for (int st = 0; st < 4; ++st) {
                    if (st <= mt) {
                        bf16x8 bk = zf;
                        if (lane < 32)
                            bk = *(const bf16x8*)&kB[(rbase + st * 16 + l15) * RLD + h * 16 + lg * 8];
                        sfr[st] = MFMA16(aq, bk, sfr[st]);
                    }
                }
                // in-register causal softmax (rows = lg*4+r, reduce over 16-lane group)
                #pragma unroll
                for (int r = 0; r < 4; ++r) {
                    int row = mt * 16 + lg * 4 + r;
                    float sv[4]; float mx = -3.0e38f;
                    #pragma unroll
                    for (int st = 0; st < 4; ++st) {
                        int col = st * 16 + l15;
                        bool ok = (st <= mt) && (col <= row);
                        sv[st] = ok ? sfr[st][r] * 0.25f : -3.0e38f;
                        mx = fmaxf(mx, sv[st]);
                    }
                    #pragma unroll
                    for (int off = 1; off < 16; off <<= 1) mx = fmaxf(mx, __shfl_xor(mx, off));
                    float e[4]; float sum = 0.f;
                    #pragma unroll
                    for (int st = 0; st < 4; ++st) {
                        e[st] = (sv[st] > -1.0e38f) ? __expf(sv[st] - mx) : 0.f;
                        sum += e[st];
                    }
                    #pragma unroll
                    for (int off = 1; off < 16; off <<= 1) sum += __shfl_xor(sum, off);
                    float inv = 1.0f / sum;
                    #pragma unroll
                    for (int st = 0; st < 4; ++st)
                        pw[(lg * 4 + r) * VLD + st * 16 + l15] = f2bf(e[st] * inv);
                }
                // PV: [16x64] @ [64x16]
                f32x4 oc = {0.f,0.f,0.f,0.f};
                #pragma unroll
                for (int kt = 0; kt < 2; ++kt) {
                    bf16x8 ap = *(const bf16x8*)&pw[l15 * VLD + kt * 32 + lg * 8];
                    bf16x8 bv = *(const bf16x8*)&vB[((bb * 8 + h) * 16 + l15) * VLD + kt * 32 + lg * 8];
                    oc = MFMA16(ap, bv, oc);
                }
                int orow = rbase + mt * 16 + lg * 4;
                #pragma unroll
                for (int r = 0; r < 4; ++r)
                    hB[(orow + r) * RLD + h * 16 + l15] = f2bf(oc[r]);
            }
        }
    }
    __syncthreads();

    // ---------------- proj + residual: x2 = x + attn @ Wp + bp -> kB ----------------
    {
        bf16x8 pa[2][4];
        #pragma unroll
        for (int i = 0; i < 2; ++i)
            #pragma unroll
            for (int kt = 0; kt < 4; ++kt)
                pa[i][kt] = *(const bf16x8*)&hB[((rt0 + i) * 16 + l15) * RLD + kt * 32 + lg * 8];
        #pragma unroll 1
        for (int ntl = 0; ntl < 4; ++ntl) {
            int nt = cg * 4 + ntl;
            f32x4 c0 = {0.f,0.f,0.f,0.f}, c1 = {0.f,0.f,0.f,0.f};
            #pragma unroll
            for (int kt = 0; kt < 4; ++kt) {
                bf16x8 b = *(const bf16x8*)&wpk[OP + ((nt * 4 + kt) * 64 + lane) * 8];
                c0 = MFMA16(pa[0][kt], b, c0);
                c1 = MFMA16(pa[1][kt], b, c1);
            }
            int col = nt * 16 + l15;
            float bpv = bp[col];
            int row0 = rt0 * 16 + lg * 4;
            #pragma unroll
            for (int r = 0; r < 4; ++r) {
                kB[(row0 + r)      * RLD + col] = f2bf(xb[(row0 + r)      * CC + col] + c0[r] + bpv);
                kB[(row0 + 16 + r) * RLD + col] = f2bf(xb[(row0 + 16 + r) * CC + col] + c1[r] + bpv);
            }
        }
    }
    __syncthreads();

    // ---------------- LN2: kB(x2) -> qB(h2) ----------------
    {
        float ga = g2[lane], gb = g2[lane + 64], ba = be2[lane], bb = be2[lane + 64];
        for (int r = wave * 16; r < wave * 16 + 16; ++r) {
            float v0 = bf2f(kB[r * RLD + lane]), v1 = bf2f(kB[r * RLD + lane + 64]);
            float s = v0 + v1;
            #pragma unroll
            for (int off = 32; off; off >>= 1) s += __shfl_xor(s, off);
            float mean = s * (1.0f / CC);
            float d0 = v0 - mean, d1 = v1 - mean;
            float sq = d0 * d0 + d1 * d1;
            #pragma unroll
            for (int off = 32; off; off >>= 1) sq += __shfl_xor(sq, off);
            float rstd = rsqrtf(sq * (1.0f / CC) + 1e-5f);
            qB[r * RLD + lane]      = f2bf(ga * (d0 * rstd) + ba);
            qB[r * RLD + lane + 64] = f2bf(gb * (d1 * rstd) + bb);
        }
    }
    __syncthreads();

    // ---------------- FF: out = x2 + gelu(h2@W1+b1)@W2 + b2 ----------------
    {
        unsigned short* f1 = vB;   // reuse as [128][RLD] chunk buffer
        bf16x8 ha[2][4];
        #pragma unroll
        for (int i = 0; i < 2; ++i)
            #pragma unroll
            for (int kt = 0; kt < 4; ++kt)
                ha[i][kt] = *(const bf16x8*)&qB[((rt0 + i) * 16 + l15) * RLD + kt * 32 + lg * 8];
        f32x4 facc[2][4];
        #pragma unroll
        for (int i = 0; i < 2; ++i)
            #pragma unroll
            for (int n = 0; n < 4; ++n) facc[i][n] = (f32x4){0.f,0.f,0.f,0.f};

        #pragma unroll 1
        for (int jc = 0; jc < 4; ++jc) {
            // FF1 chunk: gelu(h2 @ W1[:, jc*128 : jc*128+128] + b1) -> f1
            #pragma unroll 1
            for (int ntl = 0; ntl < 4; ++ntl) {
                int ntg = jc * 8 + cg * 4 + ntl;
                f32x4 c0 = {0.f,0.f,0.f,0.f}, c1 = {0.f,0.f,0.f,0.f};
                #pragma unroll
                for (int kt = 0; kt < 4; ++kt) {
                    bf16x8 b = *(const bf16x8*)&wpk[O1 + ((ntg * 4 + kt) * 64 + lane) * 8];
                    c0 = MFMA16(ha[0][kt], b, c0);
                    c1 = MFMA16(ha[1][kt], b, c1);
                }
                int colg = ntg * 16 + l15;
                float b1v = b1[colg];
                int colc = (cg * 4 + ntl) * 16 + l15;
                int row0 = rt0 * 16 + lg * 4;
                #pragma unroll
                for (int r = 0; r < 4; ++r) {
                    f1[(row0 + r)      * RLD + colc] = f2bf(gelu_exact(c0[r] + b1v));
                    f1[(row0 + 16 + r) * RLD + colc] = f2bf(gelu_exact(c1[r] + b1v));
                }
            }
            __syncthreads();
            // FF2 partial: facc += f1 @ W2[jc*128 : jc*128+128, wave's cols]
            #pragma unroll 1
            for (int kt = 0; kt < 4; ++kt) {
                int ktg = jc * 4 + kt;
                bf16x8 a0 = *(const bf16x8*)&f1[(rt0 * 16 + l15)       * RLD + kt * 32 + lg * 8];
                bf16x8 a1 = *(const bf16x8*)&f1[((rt0 + 1) * 16 + l15) * RLD + kt * 32 + lg * 8];
                #pragma unroll
                for (int ntl = 0; ntl < 4; ++ntl) {
                    int nt = cg * 4 + ntl;
                    bf16x8 b = *(const bf16x8*)&wpk[O2 + ((nt * 16 + ktg) * 64 + lane) * 8];
                    facc[0][ntl] = MFMA16(a0, b, facc[0][ntl]);
                    facc[1][ntl] = MFMA16(a1, b, facc[1][ntl]);
                }
            }
            __syncthreads();
        }

        // epilogue: out = x2 + ff + b2
        #pragma unroll
        for (int ntl = 0; ntl < 4; ++ntl) {
            int col = (cg * 4 + ntl) * 16 + l15;
            float b2v = b2[col];
            int row0 = rt0 * 16 + lg * 4;
            #pragma unroll
            for (int r = 0; r < 4; ++r) {
                ob[(row0 + r)      * CC + col] = bf2f(kB[(row0 + r)      * RLD + col]) + facc[0][ntl][r] + b2v;
                ob[(row0 + 16 + r) * CC + col] = bf2f(kB[(row0 + 16 + r) * RLD + col]) + facc[1][ntl][r] + b2v;
            }
        }
    }
}

extern "C" void kernel_launch(void* const* d_in, const int* in_sizes, int n_in,
                              void* d_out, int out_size, void* d_ws, size_t ws_size,
                              hipStream_t stream) {
    (void)n_in; (void)out_size; (void)ws_size;
    const float* x   = (const float*)d_in[0];
    const float* wq  = (const float*)d_in[1];
    const float* wk  = (const float*)d_in[2];
    const float* wv  = (const float*)d_in[3];
    const float* wp  = (const float*)d_in[4];
    const float* bp  = (const float*)d_in[5];
    const float* w1  = (const float*)d_in[6];
    const float* b1  = (const float*)d_in[7];
    const float* w2  = (const float*)d_in[8];
    const float* b2  = (const float*)d_in[9];
    const float* g1  = (const float*)d_in[10];
    const float* be1 = (const float*)d_in[11];
    const float* g2  = (const float*)d_in[12];
    const float* be2 = (const float*)d_in[13];

    unsigned short* ws16 = (unsigned short*)d_ws;
    pack_w<<<64,  256, 0, stream>>>(wq, ws16 + OQ,  128, 128, 1);
    pack_w<<<64,  256, 0, stream>>>(wk, ws16 + OKk, 128, 128, 1);
    pack_w<<<64,  256, 0, stream>>>(wv, ws16 + OV,  128, 128, 1);
    pack_w<<<64,  256, 0, stream>>>(wp, ws16 + OP,  128, 128, 0);
    pack_w<<<256, 256, 0, stream>>>(w1, ws16 + O1,  128, 512, 0);
    pack_w<<<256, 256, 0, stream>>>(w2, ws16 + O2,  512, 128, 0);

    int nblk = in_sizes[0] / (128 * CC);   // B/2 blocks (2 batch elements per block)
    block_fused<<<dim3(nblk), dim3(512), 0, stream>>>(
        x, ws16, bp, b1, b2, g1, be1, g2, be2, (float*)d_out);
}

// Round 3
// 245.762 us; speedup vs baseline: 7.2754x; 1.4230x over previous
//
#include <hip/hip_runtime.h>
#include <math.h>

#define CC  128
#define RLD 136            // halves stride for [64][128] bf16 LDS tiles (272B)
#define VLD 72             // halves stride for vT / P buffers (144B)

typedef __attribute__((ext_vector_type(8))) short bf16x8;
typedef __attribute__((ext_vector_type(4))) float f32x4;

#define MFMA16(a, b, c) __builtin_amdgcn_mfma_f32_16x16x32_bf16((a), (b), (c), 0, 0, 0)

__device__ __forceinline__ unsigned short f2bf(float f) {
    unsigned int u = __float_as_uint(f);
    u += 0x7FFFu + ((u >> 16) & 1u);       // round-to-nearest-even
    return (unsigned short)(u >> 16);
}
__device__ __forceinline__ float bf2f(unsigned short h) {
    return __uint_as_float(((unsigned int)h) << 16);
}
__device__ __forceinline__ float gelu_exact(float v) {
    return 0.5f * v * (1.0f + erff(v * 0.70710678118654752f));
}

// ---- weight pre-pack: fragment-major bf16 ----
// dst[((nt*KT + kt)*64 + lane)*8 + j] = W[kt*32 + (lane>>4)*8 + j][nt*16 + (lane&15)]
// mode 0: W row-major [K][N]; mode 1: qkv [H][K][16] with n = h*16 + d
__global__ void pack_w(const float* __restrict__ src, unsigned short* __restrict__ dst,
                       int K, int N, int mode) {
    int i = blockIdx.x * 256 + threadIdx.x;
    if (i >= K * N) return;
    int j   = i & 7;
    int l   = (i >> 3) & 63;
    int tkt = i >> 9;
    int KT  = K >> 5;
    int nt  = tkt / KT;
    int kt  = tkt - nt * KT;
    int k   = kt * 32 + (l >> 4) * 8 + j;
    int n   = nt * 16 + (l & 15);
    float v = (mode == 0) ? src[k * N + n]
                          : src[(n >> 4) * (K * 16) + k * 16 + (n & 15)];
    dst[i] = f2bf(v);
}

// packed-weight half offsets in d_ws
#define OQ  0
#define OKk 16384
#define OV  32768
#define OP  49152
#define O1  65536
#define O2  131072

// One block = 1 batch element (64 rows). 512 threads = 8 waves. ~70 KB LDS -> 2 blocks/CU.
__global__ __launch_bounds__(512, 4) void block_fused(
    const float* __restrict__ x,
    const unsigned short* __restrict__ wpk,
    const float* __restrict__ bp,
    const float* __restrict__ b1, const float* __restrict__ b2,
    const float* __restrict__ g1, const float* __restrict__ be1,
    const float* __restrict__ g2, const float* __restrict__ be2,
    float* __restrict__ out)
{
    __shared__ __align__(16) unsigned short A [9216];  // h -> P tiles (8 x 16 x 72) -> h2
    __shared__ __align__(16) unsigned short Bq[8704];  // q -> attn concat
    __shared__ __align__(16) unsigned short Ck[8704];  // k -> x2
    __shared__ __align__(16) unsigned short Vv[9216];  // vT [8h*16d][72] -> f1 chunk [64][136]

    const int tid  = threadIdx.x;
    const int lane = tid & 63;
    const int wave = tid >> 6;
    const int l15  = lane & 15;
    const int lg   = lane >> 4;

    const float* xb = x   + (size_t)blockIdx.x * (64 * CC);
    float*       ob = out + (size_t)blockIdx.x * (64 * CC);

    // ---------------- LN1: x -> A (h, bf16) ----------------
    {
        float ga = g1[lane], gb = g1[lane + 64], ba = be1[lane], bb = be1[lane + 64];
        for (int r = wave * 8; r < wave * 8 + 8; ++r) {
            float v0 = xb[r * CC + lane], v1 = xb[r * CC + lane + 64];
            float s = v0 + v1;
            #pragma unroll
            for (int off = 32; off; off >>= 1) s += __shfl_xor(s, off);
            float mean = s * (1.0f / CC);
            float d0 = v0 - mean, d1 = v1 - mean;
            float sq = d0 * d0 + d1 * d1;
            #pragma unroll
            for (int off = 32; off; off >>= 1) sq += __shfl_xor(sq, off);
            float rstd = rsqrtf(sq * (1.0f / CC) + 1e-5f);
            A[r * RLD + lane]      = f2bf(ga * (d0 * rstd) + ba);
            A[r * RLD + lane + 64] = f2bf(gb * (d1 * rstd) + bb);
        }
    }
    __syncthreads();

    const int rt  = wave >> 1;          // row tile 0..3 (16 rows each)
    const int cg  = wave & 1;           // column-group split
    const int row0 = rt * 16 + lg * 4;  // C-fragment write base row

    // ---------------- QKV: A(h) @ Wqkv -> Bq(q), Ck(k), Vv(vT) ----------------
    {
        bf16x8 la[4];
        #pragma unroll
        for (int kt = 0; kt < 4; ++kt)
            la[kt] = *(const bf16x8*)&A[(rt * 16 + l15) * RLD + kt * 32 + lg * 8];

        #pragma unroll 1
        for (int ntl = 0; ntl < 12; ++ntl) {
            int nt = cg * 12 + ntl;                 // 0..23: 0-7 q, 8-15 k, 16-23 v
            int sec = nt >> 3, ntn = nt & 7;
            const unsigned short* wb = wpk + sec * 16384;
            f32x4 c = {0.f, 0.f, 0.f, 0.f};
            #pragma unroll
            for (int kt = 0; kt < 4; ++kt) {
                bf16x8 b = *(const bf16x8*)&wb[((ntn * 4 + kt) * 64 + lane) * 8];
                c = MFMA16(la[kt], b, c);
            }
            if (sec == 0) {
                #pragma unroll
                for (int r = 0; r < 4; ++r)
                    Bq[(row0 + r) * RLD + ntn * 16 + l15] = f2bf(c[r]);
            } else if (sec == 1) {
                #pragma unroll
                for (int r = 0; r < 4; ++r)
                    Ck[(row0 + r) * RLD + ntn * 16 + l15] = f2bf(c[r]);
            } else {   // v, transposed: Vv[(h*16 + d)*VLD + s]
                #pragma unroll
                for (int r = 0; r < 4; ++r)
                    Vv[(ntn * 16 + l15) * VLD + (row0 + r)] = f2bf(c[r]);
            }
        }
    }
    __syncthreads();

    // ---------------- attention: wave = head ----------------
    {
        unsigned short* pw = A + wave * 16 * VLD;   // P tile [16][64] (overlays h, dead)
        const int hcol = wave * 16;
        f32x4 ocs[4];
        bf16x8 zf = {0, 0, 0, 0, 0, 0, 0, 0};

        #pragma unroll 1
        for (int mt = 0; mt < 4; ++mt) {
            // scores S = q @ k^T (K=16; lanes>=32 feed zeros)
            f32x4 sfr[4];
            #pragma unroll
            for (int st = 0; st < 4; ++st) sfr[st] = (f32x4){0.f, 0.f, 0.f, 0.f};
            bf16x8 aq = zf;
            if (lane < 32)
                aq = *(const bf16x8*)&Bq[(mt * 16 + l15) * RLD + hcol + lg * 8];
            #pragma unroll
            for (int st = 0; st < 4; ++st) {
                if (st <= mt) {
                    bf16x8 bk = zf;
                    if (lane < 32)
                        bk = *(const bf16x8*)&Ck[(st * 16 + l15) * RLD + hcol + lg * 8];
                    sfr[st] = MFMA16(aq, bk, sfr[st]);
                }
            }
            // causal softmax (row = mt*16 + lg*4 + r; reduce over 16-lane group)
            #pragma unroll
            for (int r = 0; r < 4; ++r) {
                int row = mt * 16 + lg * 4 + r;
                float sv[4]; float mx = -3.0e38f;
                #pragma unroll
                for (int st = 0; st < 4; ++st) {
                    int col = st * 16 + l15;
                    bool ok = (st <= mt) && (col <= row);
                    sv[st] = ok ? sfr[st][r] * 0.25f : -3.0e38f;
                    mx = fmaxf(mx, sv[st]);
                }
                #pragma unroll
                for (int off = 1; off < 16; off <<= 1) mx = fmaxf(mx, __shfl_xor(mx, off));
                float e[4]; float sum = 0.f;
                #pragma unroll
                for (int st = 0; st < 4; ++st) {
                    e[st] = (sv[st] > -1.0e38f) ? __expf(sv[st] - mx) : 0.f;
                    sum += e[st];
                }
                #pragma unroll
                for (int off = 1; off < 16; off <<= 1) sum += __shfl_xor(sum, off);
                float inv = 1.0f / sum;
                #pragma unroll
                for (int st = 0; st < 4; ++st)
                    pw[(lg * 4 + r) * VLD + st * 16 + l15] = f2bf(e[st] * inv);
            }
            // PV: [16x64] @ [64x16] -> stash in registers
            f32x4 oc = {0.f, 0.f, 0.f, 0.f};
            #pragma unroll
            for (int kt = 0; kt < 2; ++kt) {
                bf16x8 ap = *(const bf16x8*)&pw[l15 * VLD + kt * 32 + lg * 8];
                bf16x8 bv = *(const bf16x8*)&Vv[(hcol + l15) * VLD + kt * 32 + lg * 8];
                oc = MFMA16(ap, bv, oc);
            }
            ocs[mt] = oc;
        }
        __syncthreads();   // all waves done reading q (Bq) and k/v
        #pragma unroll
        for (int mt = 0; mt < 4; ++mt)
            #pragma unroll
            for (int r = 0; r < 4; ++r)
                Bq[(mt * 16 + lg * 4 + r) * RLD + hcol + l15] = f2bf(ocs[mt][r]);
    }
    __syncthreads();

    // ---------------- proj + residual: x2 = x + attn @ Wp + bp -> Ck ----------------
    {
        bf16x8 pa[4];
        #pragma unroll
        for (int kt = 0; kt < 4; ++kt)
            pa[kt] = *(const bf16x8*)&Bq[(rt * 16 + l15) * RLD + kt * 32 + lg * 8];
        #pragma unroll 1
        for (int ntl = 0; ntl < 4; ++ntl) {
            int nt = cg * 4 + ntl;
            f32x4 c = {0.f, 0.f, 0.f, 0.f};
            #pragma unroll
            for (int kt = 0; kt < 4; ++kt) {
                bf16x8 b = *(const bf16x8*)&wpk[OP + ((nt * 4 + kt) * 64 + lane) * 8];
                c = MFMA16(pa[kt], b, c);
            }
            int col = nt * 16 + l15;
            float bpv = bp[col];
            #pragma unroll
            for (int r = 0; r < 4; ++r)
                Ck[(row0 + r) * RLD + col] = f2bf(xb[(row0 + r) * CC + col] + c[r] + bpv);
        }
    }
    __syncthreads();

    // ---------------- LN2: Ck(x2) -> A(h2) ----------------
    {
        float ga = g2[lane], gb = g2[lane + 64], ba = be2[lane], bb = be2[lane + 64];
        for (int r = wave * 8; r < wave * 8 + 8; ++r) {
            float v0 = bf2f(Ck[r * RLD + lane]), v1 = bf2f(Ck[r * RLD + lane + 64]);
            float s = v0 + v1;
            #pragma unroll
            for (int off = 32; off; off >>= 1) s += __shfl_xor(s, off);
            float mean = s * (1.0f / CC);
            float d0 = v0 - mean, d1 = v1 - mean;
            float sq = d0 * d0 + d1 * d1;
            #pragma unroll
            for (int off = 32; off; off >>= 1) sq += __shfl_xor(sq, off);
            float rstd = rsqrtf(sq * (1.0f / CC) + 1e-5f);
            A[r * RLD + lane]      = f2bf(ga * (d0 * rstd) + ba);
            A[r * RLD + lane + 64] = f2bf(gb * (d1 * rstd) + bb);
        }
    }
    __syncthreads();

    // ---------------- FF: out = x2 + gelu(h2@W1+b1)@W2 + b2 ----------------
    {
        unsigned short* f1 = Vv;   // [64][RLD] chunk buffer (vT dead)
        bf16x8 ha[4];
        #pragma unroll
        for (int kt = 0; kt < 4; ++kt)
            ha[kt] = *(const bf16x8*)&A[(rt * 16 + l15) * RLD + kt * 32 + lg * 8];
        f32x4 facc[4];
        #pragma unroll
        for (int n = 0; n < 4; ++n) facc[n] = (f32x4){0.f, 0.f, 0.f, 0.f};

        #pragma unroll 1
        for (int jc = 0; jc < 4; ++jc) {
            // FF1 chunk: gelu(h2 @ W1[:, jc*128 : +128] + b1) -> f1
            #pragma unroll 1
            for (int ntl = 0; ntl < 4; ++ntl) {
                int ntg = jc * 8 + cg * 4 + ntl;
                f32x4 c = {0.f, 0.f, 0.f, 0.f};
                #pragma unroll
                for (int kt = 0; kt < 4; ++kt) {
                    bf16x8 b = *(const bf16x8*)&wpk[O1 + ((ntg * 4 + kt) * 64 + lane) * 8];
                    c = MFMA16(ha[kt], b, c);
                }
                float b1v = b1[ntg * 16 + l15];
                int colc = (cg * 4 + ntl) * 16 + l15;
                #pragma unroll
                for (int r = 0; r < 4; ++r)
                    f1[(row0 + r) * RLD + colc] = f2bf(gelu_exact(c[r] + b1v));
            }
            __syncthreads();
            // FF2 partial: facc += f1 @ W2[jc*128 : +128, cols]
            #pragma unroll 1
            for (int kt = 0; kt < 4; ++kt) {
                int ktg = jc * 4 + kt;
                bf16x8 a0 = *(const bf16x8*)&f1[(rt * 16 + l15) * RLD + kt * 32 + lg * 8];
                #pragma unroll
                for (int ntl = 0; ntl < 4; ++ntl) {
                    int nt = cg * 4 + ntl;
                    bf16x8 b = *(const bf16x8*)&wpk[O2 + ((nt * 16 + ktg) * 64 + lane) * 8];
                    facc[ntl] = MFMA16(a0, b, facc[ntl]);
                }
            }
            __syncthreads();
        }

        // epilogue: out = x2 + ff + b2
        #pragma unroll
        for (int ntl = 0; ntl < 4; ++ntl) {
            int col = (cg * 4 + ntl) * 16 + l15;
            float b2v = b2[col];
            #pragma unroll
            for (int r = 0; r < 4; ++r)
                ob[(row0 + r) * CC + col] =
                    bf2f(Ck[(row0 + r) * RLD + col]) + facc[ntl][r] + b2v;
        }
    }
}

extern "C" void kernel_launch(void* const* d_in, const int* in_sizes, int n_in,
                              void* d_out, int out_size, void* d_ws, size_t ws_size,
                              hipStream_t stream) {
    (void)n_in; (void)out_size; (void)ws_size;
    const float* x   = (const float*)d_in[0];
    const float* wq  = (const float*)d_in[1];
    const float* wk  = (const float*)d_in[2];
    const float* wv  = (const float*)d_in[3];
    const float* wp  = (const float*)d_in[4];
    const float* bp  = (const float*)d_in[5];
    const float* w1  = (const float*)d_in[6];
    const float* b1  = (const float*)d_in[7];
    const float* w2  = (const float*)d_in[8];
    const float* b2  = (const float*)d_in[9];
    const float* g1  = (const float*)d_in[10];
    const float* be1 = (const float*)d_in[11];
    const float* g2  = (const float*)d_in[12];
    const float* be2 = (const float*)d_in[13];

    unsigned short* ws16 = (unsigned short*)d_ws;
    pack_w<<<64,  256, 0, stream>>>(wq, ws16 + OQ,  128, 128, 1);
    pack_w<<<64,  256, 0, stream>>>(wk, ws16 + OKk, 128, 128, 1);
    pack_w<<<64,  256, 0, stream>>>(wv, ws16 + OV,  128, 128, 1);
    pack_w<<<64,  256, 0, stream>>>(wp, ws16 + OP,  128, 128, 0);
    pack_w<<<256, 256, 0, stream>>>(w1, ws16 + O1,  128, 512, 0);
    pack_w<<<256, 256, 0, stream>>>(w2, ws16 + O2,  512, 128, 0);

    int nblk = in_sizes[0] / (64 * CC);   // one block per batch element
    block_fused<<<dim3(nblk), dim3(512), 0, stream>>>(
        x, ws16, bp, b1, b2, g1, be1, g2, be2, (float*)d_out);
}

// Round 4
// 222.767 us; speedup vs baseline: 8.0264x; 1.1032x over previous
//
#include <hip/hip_runtime.h>
#include <hip/hip_bf16.h>
#include <math.h>

#define CC  128
#define RLD 136            // halves stride for [64][128] bf16 LDS tiles (272B)
#define VLD 72             // halves stride for vT / P buffers (144B)

typedef __attribute__((ext_vector_type(8))) short bf16x8;
typedef __attribute__((ext_vector_type(4))) float f32x4;

#define MFMA16(a, b, c) __builtin_amdgcn_mfma_f32_16x16x32_bf16((a), (b), (c), 0, 0, 0)

__device__ __forceinline__ unsigned short f2bf(float f) {
    unsigned int u = __float_as_uint(f);
    u += 0x7FFFu + ((u >> 16) & 1u);
    return (unsigned short)(u >> 16);
}
__device__ __forceinline__ float bf2f(unsigned short h) {
    return __uint_as_float(((unsigned int)h) << 16);
}
// pair convert -> v_cvt_pk_bf16_f32 (compiler lowers the standard cast; m240)
__device__ __forceinline__ unsigned int f2bf2u(float lo, float hi) {
    __hip_bfloat162 h = __float22bfloat162_rn(make_float2(lo, hi));
    union { __hip_bfloat162 h2; unsigned int u; } cv; cv.h2 = h;
    return cv.u;
}
// branch-free gelu: Phi via Abramowitz-Stegun 26.2.17 (|err| < 7.5e-8)
__device__ __forceinline__ float gelu_fast(float v) {
    float ax  = fabsf(v);
    float t   = __builtin_amdgcn_rcpf(fmaf(0.2316419f, ax, 1.0f));
    float phi = 0.39894228f * __expf(-0.5f * ax * ax);
    float p   = t * fmaf(t, fmaf(t, fmaf(t, fmaf(t, 1.330274429f, -1.821255978f),
                                   1.781477937f), -0.356563782f), 0.319381530f);
    float cpos = fmaf(-phi, p, 1.0f);          // Phi(|v|)
    float c    = (v >= 0.f) ? cpos : 1.0f - cpos;
    return v * c;
}

// ---- weight pre-pack: fragment-major bf16 (scale folded in) ----
__global__ void pack_w(const float* __restrict__ src, unsigned short* __restrict__ dst,
                       int K, int N, int mode, float scale) {
    int i = blockIdx.x * 256 + threadIdx.x;
    if (i >= K * N) return;
    int j   = i & 7;
    int l   = (i >> 3) & 63;
    int tkt = i >> 9;
    int KT  = K >> 5;
    int nt  = tkt / KT;
    int kt  = tkt - nt * KT;
    int k   = kt * 32 + (l >> 4) * 8 + j;
    int n   = nt * 16 + (l & 15);
    float v = (mode == 0) ? src[k * N + n]
                          : src[(n >> 4) * (K * 16) + k * 16 + (n & 15)];
    dst[i] = f2bf(v * scale);
}

// packed-weight half offsets in d_ws
#define OQ  0
#define OKk 16384
#define OV  32768
#define OP  49152
#define O1  65536
#define O2  131072

// One block = 1 batch element (64 rows). 512 threads = 8 waves. ~70 KB LDS -> 2 blocks/CU.
__global__ __launch_bounds__(512, 4) void block_fused(
    const float* __restrict__ x,
    const unsigned short* __restrict__ wpk,
    const float* __restrict__ bp,
    const float* __restrict__ b1, const float* __restrict__ b2,
    const float* __restrict__ g1, const float* __restrict__ be1,
    const float* __restrict__ g2, const float* __restrict__ be2,
    float* __restrict__ out)
{
    __shared__ __align__(16) unsigned short A [9216];  // h -> P tiles (8 x 16 x 72) -> h2
    __shared__ __align__(16) unsigned short Bq[8704];  // q -> attn concat
    __shared__ __align__(16) unsigned short Ck[8704];  // k -> x2
    __shared__ __align__(16) unsigned short Vv[9216];  // vT [8h*16d][72] -> f1 chunk [64][136]

    const int tid  = threadIdx.x;
    const int lane = tid & 63;
    const int wave = tid >> 6;
    const int l15  = lane & 15;
    const int lg   = lane >> 4;

    const float* xb = x   + (size_t)blockIdx.x * (64 * CC);
    float*       ob = out + (size_t)blockIdx.x * (64 * CC);

    // ---------------- LN1: x -> A (h, bf16) ----------------
    {
        float ga = g1[lane], gb = g1[lane + 64], ba = be1[lane], bb = be1[lane + 64];
        for (int r = wave * 8; r < wave * 8 + 8; ++r) {
            float v0 = xb[r * CC + lane], v1 = xb[r * CC + lane + 64];
            float s = v0 + v1;
            #pragma unroll
            for (int off = 32; off; off >>= 1) s += __shfl_xor(s, off);
            float mean = s * (1.0f / CC);
            float d0 = v0 - mean, d1 = v1 - mean;
            float sq = d0 * d0 + d1 * d1;
            #pragma unroll
            for (int off = 32; off; off >>= 1) sq += __shfl_xor(sq, off);
            float rstd = __builtin_amdgcn_rsqf(sq * (1.0f / CC) + 1e-5f);
            unsigned int u = f2bf2u(fmaf(ga, d0 * rstd, ba), fmaf(gb, d1 * rstd, bb));
            A[r * RLD + lane]      = (unsigned short)u;
            A[r * RLD + lane + 64] = (unsigned short)(u >> 16);
        }
    }
    __syncthreads();

    const int rt  = wave >> 1;          // row tile 0..3 (16 rows each)
    const int cg  = wave & 1;           // column-group split
    const int row0 = rt * 16 + lg * 4;  // C-fragment write base row

    // ---------------- QKV: A(h) @ Wqkv -> Bq(q*0.25 folded), Ck(k), Vv(vT) ----------------
    {
        bf16x8 la[4];
        #pragma unroll
        for (int kt = 0; kt < 4; ++kt)
            la[kt] = *(const bf16x8*)&A[(rt * 16 + l15) * RLD + kt * 32 + lg * 8];

        #pragma unroll 1
        for (int ntl = 0; ntl < 12; ++ntl) {
            int nt = cg * 12 + ntl;                 // 0..23: 0-7 q, 8-15 k, 16-23 v
            int sec = nt >> 3, ntn = nt & 7;
            const unsigned short* wb = wpk + sec * 16384;
            f32x4 c = {0.f, 0.f, 0.f, 0.f};
            #pragma unroll
            for (int kt = 0; kt < 4; ++kt) {
                bf16x8 b = *(const bf16x8*)&wb[((ntn * 4 + kt) * 64 + lane) * 8];
                c = MFMA16(la[kt], b, c);
            }
            unsigned int u01 = f2bf2u(c[0], c[1]);
            unsigned int u23 = f2bf2u(c[2], c[3]);
            if (sec == 0) {
                int o = row0 * RLD + ntn * 16 + l15;
                Bq[o]           = (unsigned short)u01;
                Bq[o + RLD]     = (unsigned short)(u01 >> 16);
                Bq[o + 2 * RLD] = (unsigned short)u23;
                Bq[o + 3 * RLD] = (unsigned short)(u23 >> 16);
            } else if (sec == 1) {
                int o = row0 * RLD + ntn * 16 + l15;
                Ck[o]           = (unsigned short)u01;
                Ck[o + RLD]     = (unsigned short)(u01 >> 16);
                Ck[o + 2 * RLD] = (unsigned short)u23;
                Ck[o + 3 * RLD] = (unsigned short)(u23 >> 16);
            } else {   // v, transposed: rows adjacent -> one b64 store
                *(uint2*)&Vv[(ntn * 16 + l15) * VLD + row0] = make_uint2(u01, u23);
            }
        }
    }
    __syncthreads();

    // ---------------- attention: wave = head ----------------
    {
        unsigned short* pw = A + wave * 16 * VLD;   // P tile [16][64] (overlays h, dead)
        const int hcol = wave * 16;
        f32x4 ocs[4];
        bf16x8 zf = {0, 0, 0, 0, 0, 0, 0, 0};

        #pragma unroll 1
        for (int mt = 0; mt < 4; ++mt) {
            // scores S = q @ k^T (K=16; lanes>=32 feed zeros); 0.25 scale pre-folded
            f32x4 sfr[4];
            #pragma unroll
            for (int st = 0; st < 4; ++st) sfr[st] = (f32x4){0.f, 0.f, 0.f, 0.f};
            bf16x8 aq = zf;
            if (lane < 32)
                aq = *(const bf16x8*)&Bq[(mt * 16 + l15) * RLD + hcol + lg * 8];
            #pragma unroll
            for (int st = 0; st < 4; ++st) {
                if (st <= mt) {
                    bf16x8 bk = zf;
                    if (lane < 32)
                        bk = *(const bf16x8*)&Ck[(st * 16 + l15) * RLD + hcol + lg * 8];
                    sfr[st] = MFMA16(aq, bk, sfr[st]);
                }
            }
            // causal softmax; mask only binds on the diagonal sub-tile (st == mt)
            #pragma unroll
            for (int r = 0; r < 4; ++r) {
                float sv[4], e[4];
                float mx = -3.0e38f;
                #pragma unroll
                for (int st = 0; st < 4; ++st) {
                    if (st <= mt) {
                        float s = sfr[st][r];
                        if (st == mt) s = (l15 <= lg * 4 + r) ? s : -3.0e38f;
                        sv[st] = s;
                        mx = fmaxf(mx, s);
                    }
                }
                #pragma unroll
                for (int off = 1; off < 16; off <<= 1) mx = fmaxf(mx, __shfl_xor(mx, off));
                float sum = 0.f;
                #pragma unroll
                for (int st = 0; st < 4; ++st) {
                    if (st <= mt) { e[st] = __expf(sv[st] - mx); sum += e[st]; }
                }
                #pragma unroll
                for (int off = 1; off < 16; off <<= 1) sum += __shfl_xor(sum, off);
                float inv = __builtin_amdgcn_rcpf(sum);
                int ro = (lg * 4 + r) * VLD + l15;
                #pragma unroll
                for (int st = 0; st < 4; st += 2) {
                    if (st + 1 <= mt) {                 // both live: one pk, two b16
                        unsigned int u = f2bf2u(e[st] * inv, e[st + 1] * inv);
                        pw[ro + st * 16]       = (unsigned short)u;
                        pw[ro + (st + 1) * 16] = (unsigned short)(u >> 16);
                    } else if (st <= mt) {              // st live, st+1 must be zeroed
                        pw[ro + st * 16]       = f2bf(e[st] * inv);
                        pw[ro + (st + 1) * 16] = 0;
                    }
                    // st > mt: never read by PV (kt loop bounded) -> no store
                }
            }
            // PV: only K-chunks that contain live columns
            f32x4 oc = {0.f, 0.f, 0.f, 0.f};
            #pragma unroll
            for (int kt = 0; kt < 2; ++kt) {
                if (kt <= (mt >> 1)) {
                    bf16x8 ap = *(const bf16x8*)&pw[l15 * VLD + kt * 32 + lg * 8];
                    bf16x8 bv = *(const bf16x8*)&Vv[(hcol + l15) * VLD + kt * 32 + lg * 8];
                    oc = MFMA16(ap, bv, oc);
                }
            }
            ocs[mt] = oc;
        }
        __syncthreads();   // all waves done reading q (Bq) and k/v
        #pragma unroll
        for (int mt = 0; mt < 4; ++mt) {
            unsigned int u01 = f2bf2u(ocs[mt][0], ocs[mt][1]);
            unsigned int u23 = f2bf2u(ocs[mt][2], ocs[mt][3]);
            int o = (mt * 16 + lg * 4) * RLD + hcol + l15;
            Bq[o]           = (unsigned short)u01;
            Bq[o + RLD]     = (unsigned short)(u01 >> 16);
            Bq[o + 2 * RLD] = (unsigned short)u23;
            Bq[o + 3 * RLD] = (unsigned short)(u23 >> 16);
        }
    }
    __syncthreads();

    // ---------------- proj + residual: x2 = x + attn @ Wp + bp -> Ck ----------------
    {
        bf16x8 pa[4];
        #pragma unroll
        for (int kt = 0; kt < 4; ++kt)
            pa[kt] = *(const bf16x8*)&Bq[(rt * 16 + l15) * RLD + kt * 32 + lg * 8];
        #pragma unroll 1
        for (int ntl = 0; ntl < 4; ++ntl) {
            int nt = cg * 4 + ntl;
            f32x4 c = {0.f, 0.f, 0.f, 0.f};
            #pragma unroll
            for (int kt = 0; kt < 4; ++kt) {
                bf16x8 b = *(const bf16x8*)&wpk[OP + ((nt * 4 + kt) * 64 + lane) * 8];
                c = MFMA16(pa[kt], b, c);
            }
            int col = nt * 16 + l15;
            float bpv = bp[col];
            unsigned int u01 = f2bf2u(xb[(row0 + 0) * CC + col] + c[0] + bpv,
                                      xb[(row0 + 1) * CC + col] + c[1] + bpv);
            unsigned int u23 = f2bf2u(xb[(row0 + 2) * CC + col] + c[2] + bpv,
                                      xb[(row0 + 3) * CC + col] + c[3] + bpv);
            int o = row0 * RLD + col;
            Ck[o]           = (unsigned short)u01;
            Ck[o + RLD]     = (unsigned short)(u01 >> 16);
            Ck[o + 2 * RLD] = (unsigned short)u23;
            Ck[o + 3 * RLD] = (unsigned short)(u23 >> 16);
        }
    }
    __syncthreads();

    // ---------------- LN2: Ck(x2) -> A(h2) ----------------
    {
        float ga = g2[lane], gb = g2[lane + 64], ba = be2[lane], bb = be2[lane + 64];
        for (int r = wave * 8; r < wave * 8 + 8; ++r) {
            float v0 = bf2f(Ck[r * RLD + lane]), v1 = bf2f(Ck[r * RLD + lane + 64]);
            float s = v0 + v1;
            #pragma unroll
            for (int off = 32; off; off >>= 1) s += __shfl_xor(s, off);
            float mean = s * (1.0f / CC);
            float d0 = v0 - mean, d1 = v1 - mean;
            float sq = d0 * d0 + d1 * d1;
            #pragma unroll
            for (int off = 32; off; off >>= 1) sq += __shfl_xor(sq, off);
            float rstd = __builtin_amdgcn_rsqf(sq * (1.0f / CC) + 1e-5f);
            unsigned int u = f2bf2u(fmaf(ga, d0 * rstd, ba), fmaf(gb, d1 * rstd, bb));
            A[r * RLD + lane]      = (unsigned short)u;
            A[r * RLD + lane + 64] = (unsigned short)(u >> 16);
        }
    }
    __syncthreads();

    // ---------------- FF: out = x2 + gelu(h2@W1+b1)@W2 + b2 ----------------
    {
        unsigned short* f1 = Vv;   // [64][RLD] chunk buffer (vT dead)
        bf16x8 ha[4];
        #pragma unroll
        for (int kt = 0; kt < 4; ++kt)
            ha[kt] = *(const bf16x8*)&A[(rt * 16 + l15) * RLD + kt * 32 + lg * 8];
        f32x4 facc[4];
        #pragma unroll
        for (int n = 0; n < 4; ++n) facc[n] = (f32x4){0.f, 0.f, 0.f, 0.f};

        #pragma unroll 1
        for (int jc = 0; jc < 4; ++jc) {
            // FF1 chunk: gelu(h2 @ W1[:, jc*128 : +128] + b1) -> f1
            #pragma unroll 1
            for (int ntl = 0; ntl < 4; ++ntl) {
                int ntg = jc * 8 + cg * 4 + ntl;
                f32x4 c = {0.f, 0.f, 0.f, 0.f};
                #pragma unroll
                for (int kt = 0; kt < 4; ++kt) {
                    bf16x8 b = *(const bf16x8*)&wpk[O1 + ((ntg * 4 + kt) * 64 + lane) * 8];
                    c = MFMA16(ha[kt], b, c);
                }
                float b1v = b1[ntg * 16 + l15];
                unsigned int u01 = f2bf2u(gelu_fast(c[0] + b1v), gelu_fast(c[1] + b1v));
                unsigned int u23 = f2bf2u(gelu_fast(c[2] + b1v), gelu_fast(c[3] + b1v));
                int o = row0 * RLD + (cg * 4 + ntl) * 16 + l15;
                f1[o]           = (unsigned short)u01;
                f1[o + RLD]     = (unsigned short)(u01 >> 16);
                f1[o + 2 * RLD] = (unsigned short)u23;
                f1[o + 3 * RLD] = (unsigned short)(u23 >> 16);
            }
            __syncthreads();
            // FF2 partial: facc += f1 @ W2[jc*128 : +128, cols]
            #pragma unroll 1
            for (int kt = 0; kt < 4; ++kt) {
                int ktg = jc * 4 + kt;
                bf16x8 a0 = *(const bf16x8*)&f1[(rt * 16 + l15) * RLD + kt * 32 + lg * 8];
                #pragma unroll
                for (int ntl = 0; ntl < 4; ++ntl) {
                    int nt = cg * 4 + ntl;
                    bf16x8 b = *(const bf16x8*)&wpk[O2 + ((nt * 16 + ktg) * 64 + lane) * 8];
                    facc[ntl] = MFMA16(a0, b, facc[ntl]);
                }
            }
            __syncthreads();
        }

        // epilogue: out = x2 + ff + b2
        #pragma unroll
        for (int ntl = 0; ntl < 4; ++ntl) {
            int col = (cg * 4 + ntl) * 16 + l15;
            float b2v = b2[col];
            #pragma unroll
            for (int r = 0; r < 4; ++r)
                ob[(row0 + r) * CC + col] =
                    bf2f(Ck[(row0 + r) * RLD + col]) + facc[ntl][r] + b2v;
        }
    }
}

extern "C" void kernel_launch(void* const* d_in, const int* in_sizes, int n_in,
                              void* d_out, int out_size, void* d_ws, size_t ws_size,
                              hipStream_t stream) {
    (void)n_in; (void)out_size; (void)ws_size;
    const float* x   = (const float*)d_in[0];
    const float* wq  = (const float*)d_in[1];
    const float* wk  = (const float*)d_in[2];
    const float* wv  = (const float*)d_in[3];
    const float* wp  = (const float*)d_in[4];
    const float* bp  = (const float*)d_in[5];
    const float* w1  = (const float*)d_in[6];
    const float* b1  = (const float*)d_in[7];
    const float* w2  = (const float*)d_in[8];
    const float* b2  = (const float*)d_in[9];
    const float* g1  = (const float*)d_in[10];
    const float* be1 = (const float*)d_in[11];
    const float* g2  = (const float*)d_in[12];
    const float* be2 = (const float*)d_in[13];

    unsigned short* ws16 = (unsigned short*)d_ws;
    pack_w<<<64,  256, 0, stream>>>(wq, ws16 + OQ,  128, 128, 1, 0.25f);  // HD^-0.5 folded
    pack_w<<<64,  256, 0, stream>>>(wk, ws16 + OKk, 128, 128, 1, 1.0f);
    pack_w<<<64,  256, 0, stream>>>(wv, ws16 + OV,  128, 128, 1, 1.0f);
    pack_w<<<64,  256, 0, stream>>>(wp, ws16 + OP,  128, 128, 0, 1.0f);
    pack_w<<<256, 256, 0, stream>>>(w1, ws16 + O1,  128, 512, 0, 1.0f);
    pack_w<<<256, 256, 0, stream>>>(w2, ws16 + O2,  512, 128, 0, 1.0f);

    int nblk = in_sizes[0] / (64 * CC);   // one block per batch element
    block_fused<<<dim3(nblk), dim3(512), 0, stream>>>(
        x, ws16, bp, b1, b2, g1, be1, g2, be2, (float*)d_out);
}